// Round 9
// baseline (116.906 us; speedup 1.0000x reference)
//
#include <hip/hip_runtime.h>

namespace {
constexpr int FB = 9;
constexpr int DM = 128;
constexpr int FD = 1152;
constexpr float LN_EPS = 1e-5f;

typedef __attribute__((ext_vector_type(8))) short short8v;
typedef __attribute__((ext_vector_type(4))) float float4v;

// ---- ws layout ----
// f32 region (float offsets)
constexpr int WSA_F  = 0;      // A[9][384]
constexpr int WSC_F  = 3456;   // C[9][384]
constexpr int COEF_F = 6912;   // [36][40] packed score coeffs
constexpr int BF_F   = 8352;   // fused bias [384]
// byte offsets (bf16 regions)
constexpr int AVCV_B = 35840;  // [4h*2half][64][8] bf16  (8192 B)
constexpr int P2F_B  = 44032;  // [8nt*8ks][64][8] bf16   (65536 B)
constexpr int WT_B   = 109568; // [24nt*36ks][64 lane][8 j8] bf16, k8-PERMUTED (884736 B)

// ---- LDS layout (main kernel), bytes ----
constexpr int L_W1   = 0;      // 27648 + 512 zero pad: [4m][9fq][16tok x 24k] bf16 B-frags
constexpr int L_PAD  = 27648;  // 512 B zeros (guard target for lanes 48..63)
constexpr int L_GATE = 28160;  // 16384: gate unorm16 [64tok][128]   (epilogue)
constexpr int L_HF   = 44544;  // 32768: h frags [4m][8ks][1024B]     (epilogue)
constexpr int L_COEF = 28160;  // alias over gate (pre-K-loop only): 5760B
constexpr int L_SX   = 33920;  // alias: 2304B
constexpr int LDS_BYTES = 77312;

// WBP grid split
constexpr int NB_WT   = 1728;  // 2 (e,fq) pairs per block
constexpr int NB_BIAS = 384;
constexpr int NB_P2   = 128;

__device__ __forceinline__ unsigned short f2bf(float f) {
    unsigned u = __builtin_bit_cast(unsigned, f);
    u += 0x7FFFu + ((u >> 16) & 1u);
    return (unsigned short)(u >> 16);
}
__device__ __forceinline__ unsigned pk2(float lo, float hi) {
    return (unsigned)f2bf(lo) | ((unsigned)f2bf(hi) << 16);
}
#define MFMA16x32(a, b, c) __builtin_amdgcn_mfma_f32_16x16x32_bf16(a, b, c, 0, 0, 0)
} // namespace

// ---------------- P1: A/C ----------------
__global__ void precompAC(const float* __restrict__ bW, const float* __restrict__ bb,
                          const float* __restrict__ fp, const float* __restrict__ ipw,
                          const float* __restrict__ ipb, float* __restrict__ ws)
{
    __shared__ float sw[128], sc[128];
    const int f = blockIdx.x, t = threadIdx.x;
    if (t < 128) { sw[t] = bW[f * 128 + t]; sc[t] = bb[f * 128 + t] + fp[f * 128 + t]; }
    __syncthreads();
    const float* row = ipw + (size_t)t * 128;
    float a = 0.f, c = 0.f;
    for (int k = 0; k < 128; k += 4) {
        const float4 w = *(const float4*)(row + k);
        a += sw[k]*w.x + sw[k+1]*w.y + sw[k+2]*w.z + sw[k+3]*w.w;
        c += sc[k]*w.x + sc[k+1]*w.y + sc[k+2]*w.z + sc[k+3]*w.w;
    }
    ws[WSA_F + f * 384 + t] = a;
    ws[WSC_F + f * 384 + t] = c + ipb[t];
}

// ---------------- P2: score coeffs + AvCv frags (fused) ----------------
__global__ void precompScoreAvCv(const float* __restrict__ ws, unsigned short* __restrict__ avcv,
                                 float* __restrict__ wso)
{
    const int b = blockIdx.x, t = threadIdx.x;
    if (b == 0) {
        if (t >= 324) return;
        const int h = t / 81, r = t % 81, fq = r / 9, fk = r % 9;
        const float* A = ws + WSA_F;
        const float* C = ws + WSC_F;
        const float* aq = A + fq * 384 + h * 32;
        const float* ak = A + fk * 384 + 128 + h * 32;
        const float* cq = C + fq * 384 + h * 32;
        const float* ck = C + fk * 384 + 128 + h * 32;
        float s2 = 0.f, s1q = 0.f, s1k = 0.f, s0 = 0.f;
        #pragma unroll
        for (int d = 0; d < 32; ++d) {
            s2  += aq[d] * ak[d];
            s1q += aq[d] * ck[d];
            s1k += cq[d] * ak[d];
            s0  += cq[d] * ck[d];
        }
        const float sc = 0.17677669529663687f;
        float* row = wso + COEF_F + (h * 9 + fq) * 40;
        row[fk]      = s2  * sc;
        row[10 + fk] = s1q * sc;
        row[20 + fk] = s1k * sc;
        row[30 + fk] = s0  * sc;
    } else {
        const int id = (b - 1) * 512 + t;   // 4096
        if (id >= 4096) return;
        const int j = id & 7, lane = (id >> 3) & 63, hh = id >> 9;
        const int h = hh >> 1, half = hh & 1;
        const int i = h * 32 + half * 16 + (lane & 15);
        const int k = (lane >> 4) * 8 + j;
        float v = 0.f;
        if (k < 9)       v = ws[WSA_F + k * 384 + 256 + i];
        else if (k < 18) v = ws[WSC_F + (k - 9) * 384 + 256 + i];
        avcv[id] = f2bf(v);
    }
}

// ---------------- P3: WT + Bias + P2 fused (256 threads/block) ----------------
// WT part stores the gate/proj1 fused weights as B-frags with the k8
// permutation matching the in-lane ctx->A handoff:
//   A-slot (rg, j8) carries ctx k-index r = (j8>=4)*16 + 4*rg + (j8&3)
__global__ __launch_bounds__(256)
void precompWBP(const float* __restrict__ gw, const float* __restrict__ gb,
                const float* __restrict__ p1w, const float* __restrict__ p1b,
                const float* __restrict__ opw, const float* __restrict__ opb,
                const float* __restrict__ p2w,
                unsigned short* __restrict__ wt, unsigned short* __restrict__ p2f,
                float* __restrict__ ws)
{
    __shared__ float sbuf[2][128];
    const int bid = blockIdx.x, t = threadIdx.x;
    if (bid < NB_WT) {
        const int sub = t >> 7, i = t & 127;
        const int pid = bid * 2 + sub;          // 0..3455
        const int e = pid / 9, fq = pid % 9;
        const float* Win = (e < 128) ? gw + (size_t)e * FD : p1w + (size_t)(e - 128) * FD;
        sbuf[sub][i] = Win[fq * 128 + i];
        __syncthreads();
        float acc = 0.f;
        const float* sr = sbuf[sub];
        for (int s = 0; s < 128; ++s) acc += sr[s] * opw[s * 128 + i];
        // permuted-k8 B-frag index
        const int kc36 = fq * 4 + (i >> 5);
        const int r = i & 31;
        const int half = r >> 4, il = r & 15;
        const int rg = il >> 2, jj = il & 3;
        const int lane = (e & 15) + 16 * rg;
        const int j8 = half * 4 + jj;
        wt[((size_t)((e >> 4) * 36 + kc36) * 64 + lane) * 8 + j8] = f2bf(acc);
    } else if (bid < NB_WT + NB_BIAS) {
        const int e = bid - NB_WT;
        const float* Win = (e < 128) ? gw + (size_t)e * FD : p1w + (size_t)(e - 128) * FD;
        float acc = 0.f;
        for (int m = t; m < FD; m += 256) acc += Win[m] * opb[m & 127];
        #pragma unroll
        for (int off = 32; off > 0; off >>= 1) acc += __shfl_xor(acc, off);
        const int lane = t & 63, wid = t >> 6;
        if (lane == 0) sbuf[0][wid] = acc;
        __syncthreads();
        if (t == 0) {
            const float base = (e < 128) ? gb[e] : p1b[e - 128];
            ws[BF_F + e] = base + sbuf[0][0] + sbuf[0][1] + sbuf[0][2] + sbuf[0][3];
        }
    } else {
        const int id = (bid - NB_WT - NB_BIAS) * 256 + t;   // 32768
        const int j = id & 7, lane = (id >> 3) & 63, ks = (id >> 9) & 7, nt = id >> 12;
        const int i = nt * 16 + (lane & 15);
        const int r = ks * 32 + (lane >> 4) * 8 + j;
        p2f[id] = f2bf(p2w[i * 256 + r]);
    }
}

// ---------------- main fused kernel ----------------
// __launch_bounds__(512, 2): 2 waves/EU floor -> 256-reg unified budget.
// R8's (512,4) forced a 128 budget (48 AGPR acc + 64 arch) -> hot-loop spills
// (WRITE_SIZE 41MB vs 16.8MB of real output). One variable changed here.
__global__ __launch_bounds__(512, 2)
void fba_main(const float* __restrict__ x, const float* __restrict__ p2b,
              const float* __restrict__ lng, const float* __restrict__ lnb,
              const float* __restrict__ wsf,
              const unsigned short* __restrict__ avcv,
              const unsigned short* __restrict__ p2frag,
              const unsigned short* __restrict__ wtfrag,
              float* __restrict__ out)
{
    __shared__ float4 lds4[LDS_BYTES / 16];
    char* lds = (char*)lds4;
    unsigned short* w1frag = (unsigned short*)(lds + L_W1);
    unsigned short* padz   = (unsigned short*)(lds + L_PAD);
    unsigned short* gateb  = (unsigned short*)(lds + L_GATE);
    unsigned short* hfrag  = (unsigned short*)(lds + L_HF);
    float* scoef = (float*)(lds + L_COEF);
    float* sx    = (float*)(lds + L_SX);

    const int t = threadIdx.x, lane = t & 63, wid = t >> 6;
    const int col = lane & 15, rg = lane >> 4;
    const int n0 = blockIdx.x * 64;

    // zero w1frag + pad: k-slots 18..23 must read as 0; lanes>=48 read pad zeros
    const float4 z4 = {0.f, 0.f, 0.f, 0.f};
    for (int i = t; i < (L_GATE / 16); i += 512) lds4[i] = z4;
    for (int i = t; i < 1440; i += 512) scoef[i] = wsf[COEF_F + i];
    for (int i = t; i < 576;  i += 512) sx[i] = x[(size_t)n0 * FB + i];
    __syncthreads();

    // ---- Phase A: softmax; scatter w1|attn bf16 frags (B-frag layout) ----
    for (int id = t; id < 2304; id += 512) {
        const int g = id / 36, r = id - g * 36, h = r / 9, fq = r - (r / 9) * 9;
        const float* cf = scoef + (h * 9 + fq) * 40;
        const float* xg = sx + g * FB;
        const float xq = xg[fq];
        float sc[9];
        float m = -1e30f;
        #pragma unroll
        for (int fk = 0; fk < 9; ++fk) {
            const float xk = xg[fk];
            const float v = (cf[fk] * xk + cf[10 + fk]) * xq + cf[20 + fk] * xk + cf[30 + fk];
            sc[fk] = v;
            m = fmaxf(m, v);
        }
        float sum = 0.f;
        #pragma unroll
        for (int fk = 0; fk < 9; ++fk) { sc[fk] = __expf(sc[fk] - m); sum += sc[fk]; }
        const float inv = 1.f / sum;
        unsigned short* base = w1frag + ((g >> 4) * 9 + fq) * 384;
        const int gl = g & 15;
        #pragma unroll
        for (int fk = 0; fk < 9; ++fk) {
            const float a  = sc[fk] * inv;
            const float w1 = a * xg[fk];
            const int k1 = fk, k2 = 9 + fk;
            base[(gl + 16 * (k1 >> 3)) * 8 + (k1 & 7)] = f2bf(w1);
            base[(gl + 16 * (k2 >> 3)) * 8 + (k2 & 7)] = f2bf(a);
        }
    }
    __syncthreads();

    // ---- main K-loop: barrier-free, produce-one-consume-immediately. ----
    const int nt0 = wid * 3;
    float4v acc[3][4];
    #pragma unroll
    for (int q = 0; q < 3; ++q) {
        const float b = wsf[BF_F + (nt0 + q) * 16 + col];
        #pragma unroll
        for (int m = 0; m < 4; ++m) acc[q][m] = float4v{b, b, b, b};
    }
    const float4v dz = {0.f, 0.f, 0.f, 0.f};

    for (int fq = 0; fq < 9; ++fq) {
        #pragma unroll
        for (int h = 0; h < 4; ++h) {
            const int ks = fq * 4 + h;
            const short8v av0 = *(const short8v*)(avcv + ((h * 2 + 0) * 64 + lane) * 8);
            const short8v av1 = *(const short8v*)(avcv + ((h * 2 + 1) * 64 + lane) * 8);
            #pragma unroll
            for (int m = 0; m < 4; ++m) {
                const unsigned short* wp = (lane < 48)
                    ? (w1frag + (m * 9 + fq) * 384 + lane * 8)
                    : (padz + col * 8);
                const short8v bw1m = *(const short8v*)wp;
                const float4v d0 = MFMA16x32(av0, bw1m, dz);   // D[i=0..15][token]
                const float4v d1 = MFMA16x32(av1, bw1m, dz);   // D[i=16..31][token]
                const uint4 u = { pk2(d0[0], d0[1]), pk2(d0[2], d0[3]),
                                  pk2(d1[0], d1[1]), pk2(d1[2], d1[3]) };
                const short8v a8 = __builtin_bit_cast(short8v, u);
                #pragma unroll
                for (int q = 0; q < 3; ++q) {
                    const short8v bw = *(const short8v*)(wtfrag + ((size_t)((nt0 + q) * 36 + ks) * 64 + lane) * 8);
                    acc[q][m] = MFMA16x32(a8, bw, acc[q][m]);
                }
            }
        }
    }
    __syncthreads();   // w1frag/coef dead; gate/hfrag writes may begin

    // ---- epilogue: gate -> LDS unorm16, h -> hfrag bf16 ----
    #pragma unroll
    for (int q = 0; q < 3; ++q) {
        const int e = (nt0 + q) * 16 + col;
        #pragma unroll
        for (int m = 0; m < 4; ++m) {
            #pragma unroll
            for (int j = 0; j < 4; ++j) {
                const float v = acc[q][m][j];
                const int token = m * 16 + rg * 4 + j;
                if (e < 128) {
                    const float gv = 1.f / (1.f + __expf(-v));
                    gateb[token * 128 + e] = (unsigned short)(gv * 65535.f + 0.5f);
                } else {
                    const int rr = e - 128;
                    const float hv = 0.5f * v * (1.f + erff(v * 0.70710678118654752f));
                    hfrag[m * 4096 + (rr >> 5) * 512 + (rg * 4 + j + 16 * ((rr >> 3) & 3)) * 8 + (rr & 7)] = f2bf(hv);
                }
            }
        }
    }
    __syncthreads();

    // ---- proj2 MFMA + in-register LayerNorm * gate (waves 0..3) ----
    if (wid < 4) {
        const int m = wid;
        float4v y[8];
        float lg[8], lb[8];
        #pragma unroll
        for (int nt = 0; nt < 8; ++nt) {
            const int i = nt * 16 + col;
            const float b = p2b[i];
            y[nt] = float4v{b, b, b, b};
            lg[nt] = lng[i];
            lb[nt] = lnb[i];
        }
        for (int ks = 0; ks < 8; ++ks) {
            const short8v ah = *(const short8v*)(hfrag + m * 4096 + ks * 512 + lane * 8);
            #pragma unroll
            for (int nt = 0; nt < 8; ++nt) {
                const short8v bw = *(const short8v*)(p2frag + ((nt * 8 + ks) * 64 + lane) * 8);
                y[nt] = MFMA16x32(ah, bw, y[nt]);
            }
        }
        #pragma unroll
        for (int j = 0; j < 4; ++j) {
            const int token = m * 16 + rg * 4 + j;
            float s = 0.f;
            #pragma unroll
            for (int nt = 0; nt < 8; ++nt) s += y[nt][j];
            s += __shfl_xor(s, 1); s += __shfl_xor(s, 2);
            s += __shfl_xor(s, 4); s += __shfl_xor(s, 8);
            const float mu = s * (1.f / 128.f);
            float v2 = 0.f;
            #pragma unroll
            for (int nt = 0; nt < 8; ++nt) { const float dd = y[nt][j] - mu; v2 += dd * dd; }
            v2 += __shfl_xor(v2, 1); v2 += __shfl_xor(v2, 2);
            v2 += __shfl_xor(v2, 4); v2 += __shfl_xor(v2, 8);
            const float inv = rsqrtf(v2 * (1.f / 128.f) + LN_EPS);
            float* op = out + (size_t)(n0 + token) * 128;
            #pragma unroll
            for (int nt = 0; nt < 8; ++nt) {
                const int i = nt * 16 + col;
                const float gv = (float)gateb[token * 128 + i] * (1.f / 65535.f);
                op[i] = ((y[nt][j] - mu) * inv * lg[nt] + lb[nt]) * gv;
            }
        }
    }
}

extern "C" void kernel_launch(void* const* d_in, const int* in_sizes, int n_in,
                              void* d_out, int out_size, void* d_ws, size_t ws_size,
                              hipStream_t stream)
{
    const float* x          = (const float*)d_in[0];
    const float* band_W     = (const float*)d_in[1];
    const float* band_b     = (const float*)d_in[2];
    const float* freq_pos   = (const float*)d_in[3];
    const float* in_proj_w  = (const float*)d_in[4];
    const float* in_proj_b  = (const float*)d_in[5];
    const float* out_proj_w = (const float*)d_in[6];
    const float* out_proj_b = (const float*)d_in[7];
    const float* gate_w     = (const float*)d_in[8];
    const float* gate_b     = (const float*)d_in[9];
    const float* proj1_w    = (const float*)d_in[10];
    const float* proj1_b    = (const float*)d_in[11];
    const float* proj2_w    = (const float*)d_in[12];
    const float* proj2_b    = (const float*)d_in[13];
    const float* ln_g       = (const float*)d_in[14];
    const float* ln_b       = (const float*)d_in[15];
    float* outp = (float*)d_out;

    float* wsf = (float*)d_ws;
    unsigned short* avcv = (unsigned short*)((char*)d_ws + AVCV_B);
    unsigned short* p2f  = (unsigned short*)((char*)d_ws + P2F_B);
    unsigned short* wt   = (unsigned short*)((char*)d_ws + WT_B);

    const int Ntok = in_sizes[0] / FB;   // 32768
    const int nblk = Ntok / 64;          // 512

    hipLaunchKernelGGL(precompAC,       dim3(9),    dim3(384), 0, stream, band_W, band_b, freq_pos, in_proj_w, in_proj_b, wsf);
    hipLaunchKernelGGL(precompScoreAvCv,dim3(9),    dim3(512), 0, stream, wsf, avcv, wsf);
    hipLaunchKernelGGL(precompWBP,      dim3(NB_WT + NB_BIAS + NB_P2), dim3(256), 0, stream,
                       gate_w, gate_b, proj1_w, proj1_b, out_proj_w, out_proj_b, proj2_w, wt, p2f, wsf);
    hipLaunchKernelGGL(fba_main,        dim3(nblk), dim3(512), 0, stream,
                       x, proj2_b, ln_g, ln_b, wsf, avcv, p2f, wt, outp);
}

// Round 10
// 98.236 us; speedup vs baseline: 1.1901x; 1.1901x over previous
//
#include <hip/hip_runtime.h>

namespace {
constexpr int FB = 9;
constexpr int DM = 128;
constexpr int FD = 1152;
constexpr float LN_EPS = 1e-5f;
constexpr int NT = 768;   // 12 waves

typedef __attribute__((ext_vector_type(8))) short short8v;
typedef __attribute__((ext_vector_type(4))) float float4v;

// ---- ws layout ----
constexpr int WSA_F  = 0;      // A[9][384]
constexpr int WSC_F  = 3456;   // C[9][384]
constexpr int COEF_F = 6912;   // [36][40]
constexpr int BF_F   = 8352;   // fused bias [384]
constexpr int AVCV_B = 35840;  // [4h*2half][64][8] bf16
constexpr int P2F_B  = 44032;  // [8nt*8ks][64][8] bf16
constexpr int WT_B   = 109568; // [24nt*36ks][64][8] bf16, k8-PERMUTED

// ---- LDS layout (main), bytes ----
constexpr int L_W1   = 0;      // 27648 + 512 pad
constexpr int L_PAD  = 27648;
constexpr int L_GATE = 28160;  // 16384
constexpr int L_HF   = 44544;  // 32768
constexpr int L_COEF = 28160;  // alias (pre-K only)
constexpr int L_SX   = 33920;  // alias
constexpr int LDS_BYTES = 77312;

constexpr int NB_WT   = 1728;
constexpr int NB_BIAS = 384;
constexpr int NB_P2   = 128;

__device__ __forceinline__ unsigned short f2bf(float f) {
    unsigned u = __builtin_bit_cast(unsigned, f);
    u += 0x7FFFu + ((u >> 16) & 1u);
    return (unsigned short)(u >> 16);
}
// pack two floats -> two bf16 (round-half-up) in 3 VALU: add, add, v_perm_b32
__device__ __forceinline__ unsigned pkr(float lo, float hi) {
    const unsigned a = __builtin_bit_cast(unsigned, lo) + 0x8000u;
    const unsigned b = __builtin_bit_cast(unsigned, hi) + 0x8000u;
    return __builtin_amdgcn_perm(b, a, 0x07060302u);  // [lo>>16 | hi>>16<<16]
}
#define MFMA16x32(a, b, c) __builtin_amdgcn_mfma_f32_16x16x32_bf16(a, b, c, 0, 0, 0)
} // namespace

// ---------------- P1: A/C ----------------
__global__ void precompAC(const float* __restrict__ bW, const float* __restrict__ bb,
                          const float* __restrict__ fp, const float* __restrict__ ipw,
                          const float* __restrict__ ipb, float* __restrict__ ws)
{
    __shared__ float sw[128], sc[128];
    const int f = blockIdx.x, t = threadIdx.x;
    if (t < 128) { sw[t] = bW[f * 128 + t]; sc[t] = bb[f * 128 + t] + fp[f * 128 + t]; }
    __syncthreads();
    const float* row = ipw + (size_t)t * 128;
    float a = 0.f, c = 0.f;
    for (int k = 0; k < 128; k += 4) {
        const float4 w = *(const float4*)(row + k);
        a += sw[k]*w.x + sw[k+1]*w.y + sw[k+2]*w.z + sw[k+3]*w.w;
        c += sc[k]*w.x + sc[k+1]*w.y + sc[k+2]*w.z + sc[k+3]*w.w;
    }
    ws[WSA_F + f * 384 + t] = a;
    ws[WSC_F + f * 384 + t] = c + ipb[t];
}

// ---------------- P2: score coeffs + AvCv frags ----------------
__global__ void precompScoreAvCv(const float* __restrict__ ws, unsigned short* __restrict__ avcv,
                                 float* __restrict__ wso)
{
    const int b = blockIdx.x, t = threadIdx.x;
    if (b == 0) {
        if (t >= 324) return;
        const int h = t / 81, r = t % 81, fq = r / 9, fk = r % 9;
        const float* A = ws + WSA_F;
        const float* C = ws + WSC_F;
        const float* aq = A + fq * 384 + h * 32;
        const float* ak = A + fk * 384 + 128 + h * 32;
        const float* cq = C + fq * 384 + h * 32;
        const float* ck = C + fk * 384 + 128 + h * 32;
        float s2 = 0.f, s1q = 0.f, s1k = 0.f, s0 = 0.f;
        #pragma unroll
        for (int d = 0; d < 32; ++d) {
            s2  += aq[d] * ak[d];
            s1q += aq[d] * ck[d];
            s1k += cq[d] * ak[d];
            s0  += cq[d] * ck[d];
        }
        const float sc = 0.17677669529663687f;
        float* row = wso + COEF_F + (h * 9 + fq) * 40;
        row[fk]      = s2  * sc;
        row[10 + fk] = s1q * sc;
        row[20 + fk] = s1k * sc;
        row[30 + fk] = s0  * sc;
    } else {
        const int id = (b - 1) * 512 + t;   // 4096
        if (id >= 4096) return;
        const int j = id & 7, lane = (id >> 3) & 63, hh = id >> 9;
        const int h = hh >> 1, half = hh & 1;
        const int i = h * 32 + half * 16 + (lane & 15);
        const int k = (lane >> 4) * 8 + j;
        float v = 0.f;
        if (k < 9)       v = ws[WSA_F + k * 384 + 256 + i];
        else if (k < 18) v = ws[WSC_F + (k - 9) * 384 + 256 + i];
        avcv[id] = f2bf(v);
    }
}

// ---------------- P3: WT + Bias + P2 ----------------
__global__ __launch_bounds__(256)
void precompWBP(const float* __restrict__ gw, const float* __restrict__ gb,
                const float* __restrict__ p1w, const float* __restrict__ p1b,
                const float* __restrict__ opw, const float* __restrict__ opb,
                const float* __restrict__ p2w,
                unsigned short* __restrict__ wt, unsigned short* __restrict__ p2f,
                float* __restrict__ ws)
{
    __shared__ float sbuf[2][128];
    const int bid = blockIdx.x, t = threadIdx.x;
    if (bid < NB_WT) {
        const int sub = t >> 7, i = t & 127;
        const int pid = bid * 2 + sub;
        const int e = pid / 9, fq = pid % 9;
        const float* Win = (e < 128) ? gw + (size_t)e * FD : p1w + (size_t)(e - 128) * FD;
        sbuf[sub][i] = Win[fq * 128 + i];
        __syncthreads();
        float acc = 0.f;
        const float* sr = sbuf[sub];
        for (int s = 0; s < 128; ++s) acc += sr[s] * opw[s * 128 + i];
        const int kc36 = fq * 4 + (i >> 5);
        const int r = i & 31;
        const int half = r >> 4, il = r & 15;
        const int rg = il >> 2, jj = il & 3;
        const int lane = (e & 15) + 16 * rg;
        const int j8 = half * 4 + jj;
        wt[((size_t)((e >> 4) * 36 + kc36) * 64 + lane) * 8 + j8] = f2bf(acc);
    } else if (bid < NB_WT + NB_BIAS) {
        const int e = bid - NB_WT;
        const float* Win = (e < 128) ? gw + (size_t)e * FD : p1w + (size_t)(e - 128) * FD;
        float acc = 0.f;
        for (int m = t; m < FD; m += 256) acc += Win[m] * opb[m & 127];
        #pragma unroll
        for (int off = 32; off > 0; off >>= 1) acc += __shfl_xor(acc, off);
        const int lane = t & 63, wid = t >> 6;
        if (lane == 0) sbuf[0][wid] = acc;
        __syncthreads();
        if (t == 0) {
            const float base = (e < 128) ? gb[e] : p1b[e - 128];
            ws[BF_F + e] = base + sbuf[0][0] + sbuf[0][1] + sbuf[0][2] + sbuf[0][3];
        }
    } else {
        const int id = (bid - NB_WT - NB_BIAS) * 256 + t;
        const int j = id & 7, lane = (id >> 3) & 63, ks = (id >> 9) & 7, nt = id >> 12;
        const int i = nt * 16 + (lane & 15);
        const int r = ks * 32 + (lane >> 4) * 8 + j;
        p2f[id] = f2bf(p2w[i * 256 + r]);
    }
}

// ---------------- main fused kernel ----------------
// 12 waves x 2 nt: acc = 32 AGPR/wave; (768,3) -> 170-reg budget, no spill,
// 3 waves/SIMD resident (R9's 48-acc/512-thread config forced 1 block/CU).
__global__ __launch_bounds__(NT, 3)
void fba_main(const float* __restrict__ x, const float* __restrict__ p2b,
              const float* __restrict__ lng, const float* __restrict__ lnb,
              const float* __restrict__ wsf,
              const unsigned short* __restrict__ avcv,
              const unsigned short* __restrict__ p2frag,
              const unsigned short* __restrict__ wtfrag,
              float* __restrict__ out)
{
    __shared__ float4 lds4[LDS_BYTES / 16];
    char* lds = (char*)lds4;
    unsigned short* w1frag = (unsigned short*)(lds + L_W1);
    unsigned short* gateb  = (unsigned short*)(lds + L_GATE);
    unsigned short* hfrag  = (unsigned short*)(lds + L_HF);
    float* scoef = (float*)(lds + L_COEF);
    float* sx    = (float*)(lds + L_SX);

    const int t = threadIdx.x, lane = t & 63, wid = t >> 6;
    const int col = lane & 15, rg = lane >> 4;
    const int n0 = blockIdx.x * 64;

    const float4 z4 = {0.f, 0.f, 0.f, 0.f};
    for (int i = t; i < (L_GATE / 16); i += NT) lds4[i] = z4;
    for (int i = t; i < 1440; i += NT) scoef[i] = wsf[COEF_F + i];
    for (int i = t; i < 576;  i += NT) sx[i] = x[(size_t)n0 * FB + i];
    __syncthreads();

    // ---- Phase A: softmax; vectorized scatter (id -> (row, g) so 16
    // consecutive lanes write 256B contiguous; 2xb128+1xb32 per row) ----
    for (int id = t; id < 2304; id += NT) {
        const int r = id >> 6, g = id & 63;          // r = h*9+fq
        const int h = r / 9, fq = r - h * 9;
        const float* cf = scoef + (h * 9 + fq) * 40;
        const float* xg = sx + g * FB;
        const float xq = xg[fq];
        float sc[9];
        float m = -1e30f;
        #pragma unroll
        for (int fk = 0; fk < 9; ++fk) {
            const float xk = xg[fk];
            const float v = (cf[fk] * xk + cf[10 + fk]) * xq + cf[20 + fk] * xk + cf[30 + fk];
            sc[fk] = v;
            m = fmaxf(m, v);
        }
        float sum = 0.f;
        #pragma unroll
        for (int fk = 0; fk < 9; ++fk) { sc[fk] = __expf(sc[fk] - m); sum += sc[fk]; }
        const float inv = 1.f / sum;
        float a[9], w1[9];
        #pragma unroll
        for (int fk = 0; fk < 9; ++fk) {
            a[fk]  = sc[fk] * inv;
            w1[fk] = a[fk] * xg[fk];
        }
        // k-slots: 0-8 = w1[0..8], 9-17 = a[0..8]; frag short idx = (gl+16*(k>>3))*8 + (k&7)
        char* rb = (char*)(w1frag + ((g >> 4) * 9 + fq) * 384);
        const int gl = g & 15;
        const uint4 v0 = { pkr(w1[0], w1[1]), pkr(w1[2], w1[3]),
                           pkr(w1[4], w1[5]), pkr(w1[6], w1[7]) };
        const uint4 v1 = { pkr(w1[8], a[0]), pkr(a[1], a[2]),
                           pkr(a[3], a[4]),  pkr(a[5], a[6]) };
        const unsigned v2 = pkr(a[7], a[8]);
        *(uint4*)(rb + gl * 16)        = v0;   // slots 0..7
        *(uint4*)(rb + 256 + gl * 16)  = v1;   // slots 8..15
        *(unsigned*)(rb + 512 + gl * 16) = v2; // slots 16..17
    }
    __syncthreads();

    // ---- main K-loop: barrier-free. 2 nt per wave. ----
    const int nt0 = wid * 2;
    float4v acc[2][4];
    #pragma unroll
    for (int q = 0; q < 2; ++q) {
        const float b = wsf[BF_F + (nt0 + q) * 16 + col];
        #pragma unroll
        for (int m = 0; m < 4; ++m) acc[q][m] = float4v{b, b, b, b};
    }
    const float4v dz = {0.f, 0.f, 0.f, 0.f};

    for (int fq = 0; fq < 9; ++fq) {
        short8v bw1[4];
        #pragma unroll
        for (int m = 0; m < 4; ++m)
            bw1[m] = *(const short8v*)(w1frag + (m * 9 + fq) * 384 + lane * 8);
        #pragma unroll
        for (int h = 0; h < 4; ++h) {
            const int ks = fq * 4 + h;
            const short8v av0 = *(const short8v*)(avcv + ((h * 2 + 0) * 64 + lane) * 8);
            const short8v av1 = *(const short8v*)(avcv + ((h * 2 + 1) * 64 + lane) * 8);
            const short8v wt0 = *(const short8v*)(wtfrag + ((size_t)((nt0 + 0) * 36 + ks) * 64 + lane) * 8);
            const short8v wt1 = *(const short8v*)(wtfrag + ((size_t)((nt0 + 1) * 36 + ks) * 64 + lane) * 8);
            #pragma unroll
            for (int m = 0; m < 4; ++m) {
                const float4v d0 = MFMA16x32(av0, bw1[m], dz);
                const float4v d1 = MFMA16x32(av1, bw1[m], dz);
                const uint4 u = { pkr(d0[0], d0[1]), pkr(d0[2], d0[3]),
                                  pkr(d1[0], d1[1]), pkr(d1[2], d1[3]) };
                const short8v a8 = __builtin_bit_cast(short8v, u);
                acc[0][m] = MFMA16x32(a8, wt0, acc[0][m]);
                acc[1][m] = MFMA16x32(a8, wt1, acc[1][m]);
            }
        }
    }
    __syncthreads();

    // ---- epilogue: gate (wid<4) / hfrag (wid>=4) — wave-uniform branch ----
    #pragma unroll
    for (int q = 0; q < 2; ++q) {
        const int e = (nt0 + q) * 16 + col;
        #pragma unroll
        for (int m = 0; m < 4; ++m) {
            #pragma unroll
            for (int j = 0; j < 4; ++j) {
                const float v = acc[q][m][j];
                const int token = m * 16 + rg * 4 + j;
                if (e < 128) {
                    const float gv = 1.f / (1.f + __expf(-v));
                    gateb[token * 128 + e] = (unsigned short)(gv * 65535.f + 0.5f);
                } else {
                    const int rr = e - 128;
                    const float hv = 0.5f * v * (1.f + erff(v * 0.70710678118654752f));
                    hfrag[m * 4096 + (rr >> 5) * 512 + (rg * 4 + j + 16 * ((rr >> 3) & 3)) * 8 + (rr & 7)] = f2bf(hv);
                }
            }
        }
    }
    __syncthreads();

    // ---- proj2 MFMA + in-register LayerNorm * gate (waves 0..3) ----
    if (wid < 4) {
        const int m = wid;
        float4v y[8];
        float lg[8], lb[8];
        #pragma unroll
        for (int nt = 0; nt < 8; ++nt) {
            const int i = nt * 16 + col;
            const float b = p2b[i];
            y[nt] = float4v{b, b, b, b};
            lg[nt] = lng[i];
            lb[nt] = lnb[i];
        }
        for (int ks = 0; ks < 8; ++ks) {
            const short8v ah = *(const short8v*)(hfrag + m * 4096 + ks * 512 + lane * 8);
            #pragma unroll
            for (int nt = 0; nt < 8; ++nt) {
                const short8v bw = *(const short8v*)(p2frag + ((nt * 8 + ks) * 64 + lane) * 8);
                y[nt] = MFMA16x32(ah, bw, y[nt]);
            }
        }
        #pragma unroll
        for (int j = 0; j < 4; ++j) {
            const int token = m * 16 + rg * 4 + j;
            float s = 0.f;
            #pragma unroll
            for (int nt = 0; nt < 8; ++nt) s += y[nt][j];
            s += __shfl_xor(s, 1); s += __shfl_xor(s, 2);
            s += __shfl_xor(s, 4); s += __shfl_xor(s, 8);
            const float mu = s * (1.f / 128.f);
            float v2 = 0.f;
            #pragma unroll
            for (int nt = 0; nt < 8; ++nt) { const float dd = y[nt][j] - mu; v2 += dd * dd; }
            v2 += __shfl_xor(v2, 1); v2 += __shfl_xor(v2, 2);
            v2 += __shfl_xor(v2, 4); v2 += __shfl_xor(v2, 8);
            const float inv = rsqrtf(v2 * (1.f / 128.f) + LN_EPS);
            float* op = out + (size_t)(n0 + token) * 128;
            #pragma unroll
            for (int nt = 0; nt < 8; ++nt) {
                const int i = nt * 16 + col;
                const float gv = (float)gateb[token * 128 + i] * (1.f / 65535.f);
                op[i] = ((y[nt][j] - mu) * inv * lg[nt] + lb[nt]) * gv;
            }
        }
    }
}

extern "C" void kernel_launch(void* const* d_in, const int* in_sizes, int n_in,
                              void* d_out, int out_size, void* d_ws, size_t ws_size,
                              hipStream_t stream)
{
    const float* x          = (const float*)d_in[0];
    const float* band_W     = (const float*)d_in[1];
    const float* band_b     = (const float*)d_in[2];
    const float* freq_pos   = (const float*)d_in[3];
    const float* in_proj_w  = (const float*)d_in[4];
    const float* in_proj_b  = (const float*)d_in[5];
    const float* out_proj_w = (const float*)d_in[6];
    const float* out_proj_b = (const float*)d_in[7];
    const float* gate_w     = (const float*)d_in[8];
    const float* gate_b     = (const float*)d_in[9];
    const float* proj1_w    = (const float*)d_in[10];
    const float* proj1_b    = (const float*)d_in[11];
    const float* proj2_w    = (const float*)d_in[12];
    const float* proj2_b    = (const float*)d_in[13];
    const float* ln_g       = (const float*)d_in[14];
    const float* ln_b       = (const float*)d_in[15];
    float* outp = (float*)d_out;

    float* wsf = (float*)d_ws;
    unsigned short* avcv = (unsigned short*)((char*)d_ws + AVCV_B);
    unsigned short* p2f  = (unsigned short*)((char*)d_ws + P2F_B);
    unsigned short* wt   = (unsigned short*)((char*)d_ws + WT_B);

    const int Ntok = in_sizes[0] / FB;   // 32768
    const int nblk = Ntok / 64;          // 512

    hipLaunchKernelGGL(precompAC,       dim3(9),    dim3(384), 0, stream, band_W, band_b, freq_pos, in_proj_w, in_proj_b, wsf);
    hipLaunchKernelGGL(precompScoreAvCv,dim3(9),    dim3(512), 0, stream, wsf, avcv, wsf);
    hipLaunchKernelGGL(precompWBP,      dim3(NB_WT + NB_BIAS + NB_P2), dim3(256), 0, stream,
                       gate_w, gate_b, proj1_w, proj1_b, out_proj_w, out_proj_b, proj2_w, wt, p2f, wsf);
    hipLaunchKernelGGL(fba_main,        dim3(nblk), dim3(NT),  0, stream,
                       x, proj2_b, ln_g, ln_b, wsf, avcv, p2f, wt, outp);
}

// Round 11
// 93.516 us; speedup vs baseline: 1.2501x; 1.0505x over previous
//
#include <hip/hip_runtime.h>

namespace {
constexpr int FB = 9;
constexpr int FD = 1152;
constexpr float LN_EPS = 1e-5f;
constexpr int NT = 768;   // 12 waves

typedef __attribute__((ext_vector_type(8))) short short8v;
typedef __attribute__((ext_vector_type(4))) float float4v;

// ---- ws layout ----
// f32 region (float offsets)
constexpr int WSA_F  = 0;      // A[9][384]
constexpr int WSC_F  = 3456;   // C[9][384]
constexpr int COEF_F = 6912;   // [36][40] score coeffs
constexpr int BF_F   = 8352;   // fused bias [384]
constexpr int OPA_F  = 8736;   // OPA[72 = h*18+kk][128 j]  (9216 floats)
// byte offsets
constexpr int P2F_B  = 71808;  // proj2 frags [8nt*8ks][64][8] bf16 (65536 B)
constexpr int WTA_B  = 137344; // WTA frags [24nt*21ks][64][8] bf16 (516096 B)

// ---- LDS layout (main), bytes ----
// w1f A-frags: [84 rows = ks*4+m][64 units][16B] = 86016; hfrag ALIASES it
// (epilogue only). gate region [86016,102400); scoef/sx alias inside gate
// region pre-K-loop.
constexpr int LDS_BYTES = 102400;
constexpr int L_GATE = 86016;
constexpr int L_COEF = 86016;
constexpr int L_SX   = 91776;

__device__ __forceinline__ unsigned short f2bf(float f) {
    unsigned u = __builtin_bit_cast(unsigned, f);
    u += 0x7FFFu + ((u >> 16) & 1u);
    return (unsigned short)(u >> 16);
}
// pack two floats -> two bf16 (round-half-up): add, add, v_perm_b32
__device__ __forceinline__ unsigned pkr(float lo, float hi) {
    const unsigned a = __builtin_bit_cast(unsigned, lo) + 0x8000u;
    const unsigned b = __builtin_bit_cast(unsigned, hi) + 0x8000u;
    return __builtin_amdgcn_perm(b, a, 0x07060302u);
}
#define MFMA16x32(a, b, c) __builtin_amdgcn_mfma_f32_16x16x32_bf16(a, b, c, 0, 0, 0)
} // namespace

// ---------------- P1: A/C ----------------
__global__ void precompAC(const float* __restrict__ bW, const float* __restrict__ bb,
                          const float* __restrict__ fp, const float* __restrict__ ipw,
                          const float* __restrict__ ipb, float* __restrict__ ws)
{
    __shared__ float sw[128], sc[128];
    const int f = blockIdx.x, t = threadIdx.x;
    if (t < 128) { sw[t] = bW[f * 128 + t]; sc[t] = bb[f * 128 + t] + fp[f * 128 + t]; }
    __syncthreads();
    const float* row = ipw + (size_t)t * 128;
    float a = 0.f, c = 0.f;
    for (int k = 0; k < 128; k += 4) {
        const float4 w = *(const float4*)(row + k);
        a += sw[k]*w.x + sw[k+1]*w.y + sw[k+2]*w.z + sw[k+3]*w.w;
        c += sc[k]*w.x + sc[k+1]*w.y + sc[k+2]*w.z + sc[k+3]*w.w;
    }
    ws[WSA_F + f * 384 + t] = a;
    ws[WSC_F + f * 384 + t] = c + ipb[t];
}

// ---------------- P2: score coeffs + OPA[(h,kk), j] = sum_{i in h} opw[j,i]*AvCv[kk,i] ----------------
__global__ void precompScoreOPA(const float* __restrict__ ws, const float* __restrict__ opw,
                                float* __restrict__ wso)
{
    const int b = blockIdx.x, t = threadIdx.x;
    if (b == 0) {
        if (t >= 324) return;
        const int h = t / 81, r = t % 81, fq = r / 9, fk = r % 9;
        const float* A = ws + WSA_F;
        const float* C = ws + WSC_F;
        const float* aq = A + fq * 384 + h * 32;
        const float* ak = A + fk * 384 + 128 + h * 32;
        const float* cq = C + fq * 384 + h * 32;
        const float* ck = C + fk * 384 + 128 + h * 32;
        float s2 = 0.f, s1q = 0.f, s1k = 0.f, s0 = 0.f;
        #pragma unroll
        for (int d = 0; d < 32; ++d) {
            s2  += aq[d] * ak[d];
            s1q += aq[d] * ck[d];
            s1k += cq[d] * ak[d];
            s0  += cq[d] * ck[d];
        }
        const float sc = 0.17677669529663687f;
        float* row = wso + COEF_F + (h * 9 + fq) * 40;
        row[fk]      = s2  * sc;
        row[10 + fk] = s1q * sc;
        row[20 + fk] = s1k * sc;
        row[30 + fk] = s0  * sc;
    } else {
        const int id = (b - 1) * 512 + t;   // 9216 = 72 rows x 128 j
        if (id >= 9216) return;
        const int row = id >> 7, j = id & 127;
        const int h = row / 18, kk = row - h * 18;
        const float* av = (kk < 9) ? (ws + WSA_F + kk * 384 + 256)
                                   : (ws + WSC_F + (kk - 9) * 384 + 256);
        const float* op = opw + (size_t)j * 128 + h * 32;
        const float* avh = av + h * 32;
        float s = 0.f;
        #pragma unroll
        for (int ii = 0; ii < 32; ++ii) s += op[ii] * avh[ii];
        wso[OPA_F + row * 128 + j] = s;
    }
}

// ---------------- P3: fused bias + proj2 frags ----------------
__global__ __launch_bounds__(256)
void precompBP(const float* __restrict__ gw, const float* __restrict__ gb,
               const float* __restrict__ p1w, const float* __restrict__ p1b,
               const float* __restrict__ opb, const float* __restrict__ p2w,
               unsigned short* __restrict__ p2f, float* __restrict__ ws)
{
    __shared__ float sbuf[4];
    const int bid = blockIdx.x, t = threadIdx.x;
    if (bid < 384) {
        const int e = bid;
        const float* Win = (e < 128) ? gw + (size_t)e * FD : p1w + (size_t)(e - 128) * FD;
        float acc = 0.f;
        for (int m = t; m < FD; m += 256) acc += Win[m] * opb[m & 127];
        #pragma unroll
        for (int off = 32; off > 0; off >>= 1) acc += __shfl_xor(acc, off);
        const int lane = t & 63, wid = t >> 6;
        if (lane == 0) sbuf[wid] = acc;
        __syncthreads();
        if (t == 0) {
            const float base = (e < 128) ? gb[e] : p1b[e - 128];
            ws[BF_F + e] = base + sbuf[0] + sbuf[1] + sbuf[2] + sbuf[3];
        }
    } else {
        const int id = (bid - 384) * 256 + t;   // 32768
        const int j = id & 7, lane = (id >> 3) & 63, ks = (id >> 9) & 7, nt = id >> 12;
        const int i = nt * 16 + (lane & 15);
        const int r = ks * 32 + (lane >> 4) * 8 + j;
        p2f[id] = f2bf(p2w[i * 256 + r]);
    }
}

// ---------------- P4: WTA[e, K] = sum_j Win[e, fq*128+j] * OPA[(h,kk), j] -> B-frags ----------------
__global__ __launch_bounds__(256)
void precompWTA(const float* __restrict__ gw, const float* __restrict__ p1w,
                const float* __restrict__ wsf, unsigned short* __restrict__ wta)
{
    __shared__ float s_opa[9216];
    __shared__ float s_win[1152];
    const int e = blockIdx.x, t = threadIdx.x;
    for (int i = t; i < 9216; i += 256) s_opa[i] = wsf[OPA_F + i];
    const float* Win = (e < 128) ? gw + (size_t)e * FD : p1w + (size_t)(e - 128) * FD;
    for (int i = t; i < 1152; i += 256) s_win[i] = Win[i];
    __syncthreads();
    for (int K = t; K < 672; K += 256) {
        float v = 0.f;
        if (K < 648) {
            const int p = K / 18;
            const int kk = K - p * 18;
            const int fq = p % 9, h = p / 9;
            const float* wr = s_win + fq * 128;
            const float* orow = s_opa + (h * 18 + kk) * 128;
            float acc = 0.f;
            #pragma unroll 4
            for (int j = 0; j < 128; ++j) acc += wr[j] * orow[j];
            v = acc;
        }
        const int ks = K >> 5, slot = K & 31;
        const int lane = (e & 15) + 16 * (slot >> 3);
        wta[((size_t)((e >> 4) * 21 + ks) * 64 + lane) * 8 + (slot & 7)] = f2bf(v);
    }
}

// ---------------- main fused kernel ----------------
// Single GEMM K-loop: [64 tok] x [K=672] x [384 e]. No ctx MFMA, no packs.
// 12 waves = 2 m-pairs x 6 nt-quads; acc = 32 AGPR/wave.
__global__ __launch_bounds__(NT, 3)
void fba_main(const float* __restrict__ x, const float* __restrict__ p2b,
              const float* __restrict__ lng, const float* __restrict__ lnb,
              const float* __restrict__ wsf,
              const unsigned short* __restrict__ p2frag,
              const unsigned short* __restrict__ wta,
              float* __restrict__ out)
{
    __shared__ float4 lds4[LDS_BYTES / 16];
    char* lds = (char*)lds4;
    unsigned short* hfrag = (unsigned short*)lds;            // alias (epilogue)
    unsigned short* gateb = (unsigned short*)(lds + L_GATE);
    float* scoef = (float*)(lds + L_COEF);
    float* sx    = (float*)(lds + L_SX);

    const int t = threadIdx.x, lane = t & 63, wid = t >> 6;
    const int col = lane & 15, rg = lane >> 4;
    const int n0 = blockIdx.x * 64;

    // zero K-pad 648..671: rows 80..83, units 16..63
    if (t < 192) {
        const int row = 80 + t / 48, u = 16 + t % 48;
        *(float4*)(lds + row * 1024 + u * 16) = float4{0.f, 0.f, 0.f, 0.f};
    }
    for (int i = t; i < 1440; i += NT) scoef[i] = wsf[COEF_F + i];
    for (int i = t; i < 576;  i += NT) sx[i] = x[(size_t)n0 * FB + i];
    __syncthreads();

    // ---- Phase A: per (p = h*9+fq, g): softmax -> 18 bf16 -> A-frag b32 writes ----
    #pragma unroll
    for (int it = 0; it < 3; ++it) {
        const int p = wid + it * 12;        // wave-uniform, 0..35
        const int h = p / 9, fq = p - h * 9;
        const int g = lane;
        const float* cf = scoef + p * 40;
        const float* xg = sx + g * FB;
        const float xq = xg[fq];
        float sc[9];
        float m = -1e30f;
        #pragma unroll
        for (int fk = 0; fk < 9; ++fk) {
            const float xk = xg[fk];
            const float v = (cf[fk] * xk + cf[10 + fk]) * xq + cf[20 + fk] * xk + cf[30 + fk];
            sc[fk] = v;
            m = fmaxf(m, v);
        }
        float sum = 0.f;
        #pragma unroll
        for (int fk = 0; fk < 9; ++fk) { sc[fk] = __expf(sc[fk] - m); sum += sc[fk]; }
        const float inv = 1.f / sum;
        float v[18];
        #pragma unroll
        for (int fk = 0; fk < 9; ++fk) {
            const float a = sc[fk] * inv;
            v[fk]     = a * xg[fk];   // w1 type
            v[9 + fk] = a;            // attn type
        }
        const int mg = g >> 4, gl = g & 15;
        const int K0 = p * 18;
        #pragma unroll
        for (int qq = 0; qq < 9; ++qq) {
            const int K = K0 + 2 * qq;
            const int ks = K >> 5, slot = K & 31;
            const int row = ks * 4 + mg;
            const int u = gl + 16 * (slot >> 3);
            *(unsigned*)(lds + row * 1024 + u * 16 + (slot & 7) * 2) = pkr(v[2 * qq], v[2 * qq + 1]);
        }
    }
    __syncthreads();

    // ---- K-loop: pure GEMM, 21 k-steps, 8 MFMA each ----
    const int mp = wid & 1;        // m-pair: m = 2*mp + mi
    const int ng = wid >> 1;       // nt quad: nt = ng*4 + q
    float4v acc[2][4];
    #pragma unroll
    for (int q = 0; q < 4; ++q) {
        const float b = wsf[BF_F + (ng * 4 + q) * 16 + col];
        acc[0][q] = float4v{b, b, b, b};
        acc[1][q] = float4v{b, b, b, b};
    }
    #pragma unroll 3
    for (int ks = 0; ks < 21; ++ks) {
        const short8v a0 = *(const short8v*)(lds + ((ks * 4 + mp * 2 + 0) * 64 + lane) * 16);
        const short8v a1 = *(const short8v*)(lds + ((ks * 4 + mp * 2 + 1) * 64 + lane) * 16);
        #pragma unroll
        for (int q = 0; q < 4; ++q) {
            const short8v bw = *(const short8v*)(wta + ((size_t)((ng * 4 + q) * 21 + ks) * 64 + lane) * 8);
            acc[0][q] = MFMA16x32(a0, bw, acc[0][q]);
            acc[1][q] = MFMA16x32(a1, bw, acc[1][q]);
        }
    }
    __syncthreads();   // all A-reads done; hfrag (aliased) writes may begin

    // ---- epilogue: gate -> unorm16 LDS, h -> hfrag bf16 ----
    #pragma unroll
    for (int mi = 0; mi < 2; ++mi) {
        const int m = mp * 2 + mi;
        #pragma unroll
        for (int q = 0; q < 4; ++q) {
            const int e = (ng * 4 + q) * 16 + col;
            #pragma unroll
            for (int j = 0; j < 4; ++j) {
                const float vv = acc[mi][q][j];
                const int token = m * 16 + rg * 4 + j;
                if (e < 128) {
                    const float gv = 1.f / (1.f + __expf(-vv));
                    gateb[token * 128 + e] = (unsigned short)(gv * 65535.f + 0.5f);
                } else {
                    const int rr = e - 128;
                    const float hv = 0.5f * vv * (1.f + erff(vv * 0.70710678118654752f));
                    hfrag[m * 4096 + (rr >> 5) * 512 + (rg * 4 + j + 16 * ((rr >> 3) & 3)) * 8 + (rr & 7)] = f2bf(hv);
                }
            }
        }
    }
    __syncthreads();

    // ---- proj2 MFMA + in-register LayerNorm * gate (waves 0..3) ----
    if (wid < 4) {
        const int m = wid;
        float4v y[8];
        float lg[8], lb[8];
        #pragma unroll
        for (int nt = 0; nt < 8; ++nt) {
            const int i = nt * 16 + col;
            const float b = p2b[i];
            y[nt] = float4v{b, b, b, b};
            lg[nt] = lng[i];
            lb[nt] = lnb[i];
        }
        for (int ks = 0; ks < 8; ++ks) {
            const short8v ah = *(const short8v*)(hfrag + m * 4096 + ks * 512 + lane * 8);
            #pragma unroll
            for (int nt = 0; nt < 8; ++nt) {
                const short8v bw = *(const short8v*)(p2frag + ((nt * 8 + ks) * 64 + lane) * 8);
                y[nt] = MFMA16x32(ah, bw, y[nt]);
            }
        }
        #pragma unroll
        for (int j = 0; j < 4; ++j) {
            const int token = m * 16 + rg * 4 + j;
            float s = 0.f;
            #pragma unroll
            for (int nt = 0; nt < 8; ++nt) s += y[nt][j];
            s += __shfl_xor(s, 1); s += __shfl_xor(s, 2);
            s += __shfl_xor(s, 4); s += __shfl_xor(s, 8);
            const float mu = s * (1.f / 128.f);
            float v2 = 0.f;
            #pragma unroll
            for (int nt = 0; nt < 8; ++nt) { const float dd = y[nt][j] - mu; v2 += dd * dd; }
            v2 += __shfl_xor(v2, 1); v2 += __shfl_xor(v2, 2);
            v2 += __shfl_xor(v2, 4); v2 += __shfl_xor(v2, 8);
            const float inv = rsqrtf(v2 * (1.f / 128.f) + LN_EPS);
            float* op = out + (size_t)(n0 + token) * 128;
            #pragma unroll
            for (int nt = 0; nt < 8; ++nt) {
                const int i = nt * 16 + col;
                const float gv = (float)gateb[token * 128 + i] * (1.f / 65535.f);
                op[i] = ((y[nt][j] - mu) * inv * lg[nt] + lb[nt]) * gv;
            }
        }
    }
}

extern "C" void kernel_launch(void* const* d_in, const int* in_sizes, int n_in,
                              void* d_out, int out_size, void* d_ws, size_t ws_size,
                              hipStream_t stream)
{
    const float* x          = (const float*)d_in[0];
    const float* band_W     = (const float*)d_in[1];
    const float* band_b     = (const float*)d_in[2];
    const float* freq_pos   = (const float*)d_in[3];
    const float* in_proj_w  = (const float*)d_in[4];
    const float* in_proj_b  = (const float*)d_in[5];
    const float* out_proj_w = (const float*)d_in[6];
    const float* out_proj_b = (const float*)d_in[7];
    const float* gate_w     = (const float*)d_in[8];
    const float* gate_b     = (const float*)d_in[9];
    const float* proj1_w    = (const float*)d_in[10];
    const float* proj1_b    = (const float*)d_in[11];
    const float* proj2_w    = (const float*)d_in[12];
    const float* proj2_b    = (const float*)d_in[13];
    const float* ln_g       = (const float*)d_in[14];
    const float* ln_b       = (const float*)d_in[15];
    float* outp = (float*)d_out;

    float* wsf = (float*)d_ws;
    unsigned short* p2f = (unsigned short*)((char*)d_ws + P2F_B);
    unsigned short* wta = (unsigned short*)((char*)d_ws + WTA_B);

    const int Ntok = in_sizes[0] / FB;   // 32768
    const int nblk = Ntok / 64;          // 512

    hipLaunchKernelGGL(precompAC,       dim3(9),   dim3(384), 0, stream, band_W, band_b, freq_pos, in_proj_w, in_proj_b, wsf);
    hipLaunchKernelGGL(precompScoreOPA, dim3(19),  dim3(512), 0, stream, wsf, out_proj_w, wsf);
    hipLaunchKernelGGL(precompBP,       dim3(512), dim3(256), 0, stream, gate_w, gate_b, proj1_w, proj1_b, out_proj_b, proj2_w, p2f, wsf);
    hipLaunchKernelGGL(precompWTA,      dim3(384), dim3(256), 0, stream, gate_w, proj1_w, wsf, wta);
    hipLaunchKernelGGL(fba_main,        dim3(nblk), dim3(NT), 0, stream,
                       x, proj2_b, ln_g, ln_b, wsf, p2f, wta, outp);
}